// Round 7
// baseline (1754.253 us; speedup 1.0000x reference)
//
#include <hip/hip_runtime.h>
#include <hip/hip_bf16.h>

#define N_NODES 50000
#define N_EDGES 800000
#define N_GRAPHS 32
#define NODE_DIM 128
#define HIDDEN 256
#define N_LAYERS 3

typedef __attribute__((ext_vector_type(8))) short bh8;   // 8 bf16 (4 VGPRs)
typedef __attribute__((ext_vector_type(4))) short bh4;   // 4 bf16 (8B)
typedef __attribute__((ext_vector_type(4))) float f32x4; // MFMA acc

#define MP 264  // M/H tile pitch (bf16)
#define YP 136  // y_precompute X-tile pitch (bf16)
#define DQ 16   // dst nodes per edge-CSR block
#define EP2 36  // St pitch (fp32): 144B rows, 16B-aligned float4 slots
#define YDP 264 // ydc LDS pitch (shorts)
#define WSP 36  // wsh pitch (floats)
#define SCAN_BS 512
#define OB2 32  // out_stage2 blocks

// swish via hw rcp (avoids full-precision fp32 divide sequence)
__device__ __forceinline__ float swish_f(float v) {
    return v * __builtin_amdgcn_rcpf(1.0f + __expf(-v));
}

// round-half-up bf16 (2 int ops; differs from RNE only on exact ties)
__device__ __forceinline__ short f2bf(float f) {
    union { float f; unsigned u; } v;
    v.f = f;
    return (short)((v.u + 0x8000u) >> 16);
}

__device__ __forceinline__ float bf2f(short s) {
    union { unsigned u; float f; } v;
    v.u = ((unsigned)(unsigned short)s) << 16;
    return v.f;
}

// async global->LDS DMA, 16B per lane: LDS dest = base + lane*16 (wave-linear),
// global src per-lane. Zero VGPR cost; completion tracked by vmcnt.
__device__ __forceinline__ void async16(const void* g, void* l) {
    __builtin_amdgcn_global_load_lds(
        (const __attribute__((address_space(1))) void*)g,
        (__attribute__((address_space(3))) void*)l, 16, 0, 0);
}

// raw barrier that does NOT drain vmcnt (compiler __syncthreads emits
// s_waitcnt vmcnt(0) before s_barrier, which would kill in-flight DMA).
// lgkmcnt(0) drains LDS writes for cross-wave visibility.
#define LDS_BARRIER()                                          \
    do {                                                       \
        asm volatile("s_waitcnt lgkmcnt(0)" ::: "memory");     \
        __builtin_amdgcn_s_barrier();                          \
        __builtin_amdgcn_sched_barrier(0);                     \
    } while (0)

// d2[e] = |pos[dst] - pos[src] + shift @ lattice[batch[src]]|^2
__global__ void prep_kernel(const float* __restrict__ pos, const float* __restrict__ shift,
                            const float* __restrict__ lattice, const int* __restrict__ eidx,
                            const int* __restrict__ batch, float* __restrict__ d2) {
    int e = blockIdx.x * blockDim.x + threadIdx.x;
    if (e >= N_EDGES) return;
    int s = eidx[e];
    int d = eidx[N_EDGES + e];
    int b = batch[s];
    const float* lat = lattice + b * 9;
    float s0 = shift[e * 3 + 0], s1 = shift[e * 3 + 1], s2 = shift[e * 3 + 2];
    float acc = 0.f;
#pragma unroll
    for (int j = 0; j < 3; j++) {
        float v = pos[d * 3 + j] - pos[s * 3 + j] + s0 * lat[j] + s1 * lat[3 + j] + s2 * lat[6 + j];
        acc += v * v;
    }
    d2[e] = acc;
}

// x[n][c] = embed[z[n]][c]; also bf16 mirror
__global__ void embed_kernel(const float* __restrict__ emb, const int* __restrict__ z,
                             float* __restrict__ x, short* __restrict__ xb) {
    int i = blockIdx.x * blockDim.x + threadIdx.x;
    int n = i >> 7, c = i & 127;
    float v = emb[z[n] * 128 + c];
    x[i] = v;
    xb[i] = f2bf(v);
}

// out[l][h][k] = bf16(in[l][k][h]) for k<K_in else 0
__global__ void cvt_wT_kernel(const float* __restrict__ in, short* __restrict__ out,
                              int K_in, int H, int K_pad, int total) {
    int i = blockIdx.x * blockDim.x + threadIdx.x;
    if (i >= total) return;
    int k = i % K_pad;
    int t = i / K_pad;
    int h = t % H;
    int l = t / H;
    out[i] = (k < K_in) ? f2bf(in[((size_t)l * K_in + k) * H + h]) : (short)0;
}

// combined edge-W1 transpose: out[l][m][k] bf16, m<256 -> W1[l][k][m] (dst part),
// m>=256 -> W1[l][128+k][m-256] (src part). K=128 exact.
__global__ void cvt_wc_kernel(const float* __restrict__ in, short* __restrict__ out, int total) {
    int i = blockIdx.x * blockDim.x + threadIdx.x;
    if (i >= total) return;
    int k = i & 127;
    int t = i >> 7;
    int m = t & 511;
    int l = t >> 9;
    size_t src;
    if (m < 256) src = ((size_t)l * 257 + k) * 256 + m;
    else src = ((size_t)l * 257 + 128 + k) * 256 + (m - 256);
    out[i] = f2bf(in[src]);
}

// ---- CSR counting-sort build ----
__global__ void hist_kernel(const int* __restrict__ eidx, int* __restrict__ deg) {
    int e = blockIdx.x * blockDim.x + threadIdx.x;
    if (e >= N_EDGES) return;
    atomicAdd(&deg[eidx[N_EDGES + e]], 1);
}

__global__ void scan1_kernel(const int* __restrict__ deg, int* __restrict__ sc,
                             int* __restrict__ bsum, int n) {
    __shared__ int s[SCAN_BS];
    int i = blockIdx.x * SCAN_BS + threadIdx.x;
    int v = (i < n) ? deg[i] : 0;
    s[threadIdx.x] = v;
    __syncthreads();
    for (int off = 1; off < SCAN_BS; off <<= 1) {
        int t = (threadIdx.x >= off) ? s[threadIdx.x - off] : 0;
        __syncthreads();
        s[threadIdx.x] += t;
        __syncthreads();
    }
    if (i < n) sc[i] = s[threadIdx.x];
    if (threadIdx.x == SCAN_BS - 1) bsum[blockIdx.x] = s[SCAN_BS - 1];
}

__global__ void scan2_kernel(int* __restrict__ bsum, int nb) {  // 1 block, 128 threads
    __shared__ int s[128];
    int v = (threadIdx.x < nb) ? bsum[threadIdx.x] : 0;
    s[threadIdx.x] = v;
    __syncthreads();
    for (int off = 1; off < 128; off <<= 1) {
        int t = (threadIdx.x >= off) ? s[threadIdx.x - off] : 0;
        __syncthreads();
        s[threadIdx.x] += t;
        __syncthreads();
    }
    if (threadIdx.x < nb) bsum[threadIdx.x] = s[threadIdx.x];
}

__global__ void scan3_kernel(const int* __restrict__ sc, const int* __restrict__ deg,
                             const int* __restrict__ bsum, int* __restrict__ rowptr,
                             int n, int total) {
    int i = blockIdx.x * SCAN_BS + threadIdx.x;
    if (i > n) return;
    if (i == n) { rowptr[n] = total; return; }
    int off = (blockIdx.x > 0) ? bsum[blockIdx.x - 1] : 0;
    rowptr[i] = sc[i] - deg[i] + off;
}

// scatter into dst-sorted order, packing (src, dst, d2)
__global__ void fill_kernel(const int* __restrict__ eidx, const float* __restrict__ d2,
                            const int* __restrict__ rowptr, int* __restrict__ fillc,
                            int4* __restrict__ epack) {
    int e = blockIdx.x * blockDim.x + threadIdx.x;
    if (e >= N_EDGES) return;
    int s = eidx[e];
    int d = eidx[N_EDGES + e];
    int p = rowptr[d] + atomicAdd(&fillc[d], 1);
    epack[p] = make_int4(s, d, __float_as_int(d2[e]), 0);
}

// ---------------- per-layer node-level GEMM1 precompute ----------------
__global__ __launch_bounds__(256, 4) void y_precompute(
    const short* __restrict__ xb, const short* __restrict__ WcT,
    const float* __restrict__ b1, short* __restrict__ ydb, short* __restrict__ ysb) {
    __shared__ __align__(16) short B[64 * MP];  // X [64][YP] then Y [64][MP]
    const int tid = threadIdx.x;
    const int half = blockIdx.x & 1;
    const int n0 = (blockIdx.x >> 1) * 64;
    const int wv = tid >> 6;
    const int ln = tid & 63;
    const int lr = ln & 15;
    const int lq = ln >> 4;

    {
        int row = tid >> 2, p = tid & 3;
        int gn = n0 + row;
        if (gn < N_NODES) {
            const int4* xp = (const int4*)(xb + (size_t)gn * 128) + p * 4;
#pragma unroll
            for (int i = 0; i < 4; i++) *(int4*)(B + row * YP + (p * 4 + i) * 8) = xp[i];
        } else {
            int4 z4 = make_int4(0, 0, 0, 0);
#pragma unroll
            for (int i = 0; i < 4; i++) *(int4*)(B + row * YP + (p * 4 + i) * 8) = z4;
        }
    }
    __syncthreads();

    f32x4 acc[4][4];
#pragma unroll
    for (int a = 0; a < 4; a++)
#pragma unroll
        for (int b = 0; b < 4; b++) acc[a][b] = (f32x4)(0.f);

    const short* a_base = WcT + (size_t)(half * 256 + wv * 64 + lr) * 128 + lq * 8;
#pragma unroll
    for (int ks = 0; ks < 128; ks += 32) {
        bh8 af[4], bf[4];
#pragma unroll
        for (int mt = 0; mt < 4; mt++) af[mt] = *(const bh8*)(a_base + mt * 16 * 128 + ks);
#pragma unroll
        for (int nt = 0; nt < 4; nt++)
            bf[nt] = *(const bh8*)(B + (nt * 16 + lr) * YP + ks + lq * 8);
#pragma unroll
        for (int mt = 0; mt < 4; mt++)
#pragma unroll
            for (int nt = 0; nt < 4; nt++)
                acc[mt][nt] = __builtin_amdgcn_mfma_f32_16x16x32_bf16(af[mt], bf[nt],
                                                                      acc[mt][nt], 0, 0, 0);
    }
    __syncthreads();   // done reading X -> B becomes Y [64][MP]

#pragma unroll
    for (int mt = 0; mt < 4; mt++) {
        int h0 = wv * 64 + mt * 16 + lq * 4;
        float4 bb = half ? make_float4(0.f, 0.f, 0.f, 0.f) : *(const float4*)(b1 + h0);
#pragma unroll
        for (int nt = 0; nt < 4; nt++) {
            bh4 pk;
            pk[0] = f2bf(acc[mt][nt][0] + bb.x);
            pk[1] = f2bf(acc[mt][nt][1] + bb.y);
            pk[2] = f2bf(acc[mt][nt][2] + bb.z);
            pk[3] = f2bf(acc[mt][nt][3] + bb.w);
            *(bh4*)(B + (nt * 16 + lr) * MP + h0) = pk;
        }
    }
    __syncthreads();

    // coalesced copy: instr i writes 64 consecutive int4 (1KB contiguous)
    short* outp = half ? ysb : ydb;
    int4* og = (int4*)(outp + (size_t)n0 * 256);
#pragma unroll
    for (int i = 0; i < 8; i++) {
        int f = i * 256 + tid;             // flat int4 index over [64][256]
        int row = f >> 5;
        if (n0 + row < N_NODES)
            og[f] = *(const int4*)(B + row * MP + (f & 31) * 8);
    }
}

// ---------------- Edge MLP, CSR dst-centric, async-DMA pipelined ----------------
// Block owns DQ=16 dst nodes (contiguous edge range). Per-chunk ys rows are
// prefetched by __builtin_amdgcn_global_load_lds into a wave-private Ys quarter
// (zero VGPR cost -> no spills, the r5/r6 failure mode). Raw s_barrier (no vmcnt
// drain) keeps the DMA in flight across the chunk's compute phases. Ys is stored
// XOR-swizzled (16B slot c ^= el&7, applied on the per-lane GLOBAL address) so
// stage-A reads are 2-way-free instead of 8-way conflicted. Metadata (src,dl,d2)
// rotates through a 4-slot LDS ring prefetched 2 chunks ahead.
__global__ __launch_bounds__(256, 3) void edge_mlp_csr(
    const short* __restrict__ ydb, const short* __restrict__ ysb,
    const float* __restrict__ w1c,   // [256] f32: W1 row 256 (the d2 row)
    const int4* __restrict__ epack,  // dst-sorted (src, dst, d2)
    const int* __restrict__ rowptr,
    const short* __restrict__ W2T,   // [128][256] bf16
    const float* __restrict__ b2,
    float* __restrict__ agg) {
    __shared__ __align__(16) short MB[9216];        // 18432B: M [32][MP] / St [128][EP2] f32
    __shared__ __align__(16) short Ys[8192];        // 16384B: [32][256] ys rows (swizzled)
    __shared__ __align__(16) short ydc[DQ * YDP];   // 8448B
    __shared__ __align__(16) float Acc[DQ * 128];   // 8192B
    __shared__ __align__(16) float wsh[8 * WSP];    // 1152B
    __shared__ int s_src[4][32];
    __shared__ int s_dlm[4][32];
    __shared__ float s_d2m[4][32];
    float* St = (float*)MB;
    const int tid = threadIdx.x;
    const int n0 = blockIdx.x * DQ;
    const int wv = tid >> 6;
    const int ln = tid & 63;
    const int lr = ln & 15;
    const int lq = ln >> 4;
    const int el = tid >> 3;
    const int p = tid & 7;

    const int estart = rowptr[n0];
    const int eend = rowptr[n0 + DQ];
    const int nch = (eend - estart + 31) >> 5;

    // ---- phase 0: stage yd rows (coalesced), zero Acc, w1c -> wsh, meta ch0/ch1 ----
    {
        const int4* src = (const int4*)(ydb + (size_t)n0 * 256);  // 512 int4 contiguous
        int4* dst = (int4*)ydc;
#pragma unroll
        for (int i = 0; i < 2; i++) {
            int f = tid + i * 256;
            dst[(f >> 5) * 33 + (f & 31)] = src[f];   // YDP=264 shorts = 33 int4
        }
        float4* az = (float4*)Acc;
        az[tid] = make_float4(0.f, 0.f, 0.f, 0.f);
        az[tid + 256] = make_float4(0.f, 0.f, 0.f, 0.f);
        wsh[(tid >> 5) * WSP + (tid & 31)] = w1c[tid];
    }
    if (tid < 64) {
        int i = tid >> 5, j = tid & 31;
        int idx = estart + i * 32 + j;
        bool ok = idx < eend;
        int4 E = ok ? epack[idx] : make_int4(0, 0, 0, 0);
        s_src[i][j] = ok ? E.x : 0;
        s_dlm[i][j] = ok ? (E.y - n0) : -1;
        s_d2m[i][j] = __int_as_float(E.z);
    }
    __syncthreads();   // normal barrier: DMA not yet issued, drain is harmless

    // ---- DMA chunk 0 (per wave: 4 instr x 1024B into own Ys quarter) ----
    if (nch > 0) {
#pragma unroll
        for (int k = 0; k < 4; k++) {
            int elk = (wv << 3) + (k << 1) + (ln >> 5);
            int srck = s_src[0][elk];
            int ck = (ln & 31) ^ (elk & 7);
            int ub = __builtin_amdgcn_readfirstlane((wv << 11) | (k << 9));
            async16(ysb + (size_t)srck * 256 + (ck << 3), Ys + ub);
        }
    }

    for (int ch = 0; ch < nch; ch++) {
        const int cs = ch & 3, ns = (ch + 1) & 3, ps = (ch + 2) & 3;

        // wait for own wave's Ys DMA (issued last iteration / prologue)
        asm volatile("s_waitcnt vmcnt(0)" ::: "memory");
        __builtin_amdgcn_sched_barrier(0);

        // epack prefetch for ch+2 (short-lived regs, 32 threads)
        int4 Epf = make_int4(0, 0, 0, 0);
        int pidx = estart + (ch + 2) * 32 + tid;
        bool pok = (tid < 32) && (pidx < eend);
        if (pok) Epf = epack[pidx];

        // ---- stage A: m = swish(ydc[dl] + Ys[el] + d2*wsh) -> MB ----
        {
            int dl = s_dlm[cs][el];
            float d2v = s_d2m[cs][el];
            if (dl >= 0) {
                const short* yl = ydc + dl * YDP + p * 32;
                const float* wl = wsh + p * WSP;
                const short* yr = Ys + el * 256;
                const int ex = el & 7;
#pragma unroll
                for (int q = 0; q < 4; q++) {
                    bh8 bv = *(const bh8*)(yr + (((p * 4 + q) ^ ex) << 3));
                    bh8 av = *(const bh8*)(yl + q * 8);
                    float4 w0 = *(const float4*)(wl + q * 8);
                    float4 w1 = *(const float4*)(wl + q * 8 + 4);
                    float wf[8] = {w0.x, w0.y, w0.z, w0.w, w1.x, w1.y, w1.z, w1.w};
                    union { int4 v; short s2[8]; } m;
#pragma unroll
                    for (int j = 0; j < 8; j++) {
                        float f = bf2f(av[j]) + bf2f(bv[j]) + d2v * wf[j];
                        m.s2[j] = f2bf(swish_f(f));
                    }
                    *(int4*)(MB + el * MP + p * 32 + q * 8) = m.v;
                }
            } else {
                int4 z4 = make_int4(0, 0, 0, 0);
#pragma unroll
                for (int q = 0; q < 4; q++) *(int4*)(MB + el * MP + p * 32 + q * 8) = z4;
            }
        }

        // meta store for ch+2 (waits only the epack load: DMA not yet issued)
        if (tid < 32) {
            s_src[ps][tid] = pok ? Epf.x : 0;
            s_dlm[ps][tid] = pok ? (Epf.y - n0) : -1;
            s_d2m[ps][tid] = pok ? __int_as_float(Epf.z) : 0.f;
        }

        // ---- issue DMA for ch+1 into own Ys quarter (own wave done reading it) ----
        if (ch + 1 < nch) {
#pragma unroll
            for (int k = 0; k < 4; k++) {
                int elk = (wv << 3) + (k << 1) + (ln >> 5);
                int srck = s_src[ns][elk];
                int ck = (ln & 31) ^ (elk & 7);
                int ub = __builtin_amdgcn_readfirstlane((wv << 11) | (k << 9));
                async16(ysb + (size_t)srck * 256 + (ck << 3), Ys + ub);
            }
        }
        LDS_BARRIER();   // M complete; DMA stays in flight

        // ---- GEMM2: 128 ch x 32 edges, each wave 32 ch ----
        float4 sv[2][2];
        {
            f32x4 acc[2][2];
#pragma unroll
            for (int a = 0; a < 2; a++)
#pragma unroll
                for (int b = 0; b < 2; b++) acc[a][b] = (f32x4)(0.f);

            const short* a_base = W2T + (size_t)(wv * 32 + lr) * 256 + lq * 8;
            for (int ks = 0; ks < 256; ks += 32) {
                bh8 af[2], bf[2];
#pragma unroll
                for (int mt = 0; mt < 2; mt++) af[mt] = *(const bh8*)(a_base + mt * 16 * 256 + ks);
#pragma unroll
                for (int nt = 0; nt < 2; nt++)
                    bf[nt] = *(const bh8*)(MB + (nt * 16 + lr) * MP + ks + lq * 8);
#pragma unroll
                for (int mt = 0; mt < 2; mt++)
#pragma unroll
                    for (int nt = 0; nt < 2; nt++)
                        acc[mt][nt] = __builtin_amdgcn_mfma_f32_16x16x32_bf16(af[mt], bf[nt],
                                                                              acc[mt][nt], 0, 0, 0);
            }
#pragma unroll
            for (int mt = 0; mt < 2; mt++) {
                int c0 = wv * 32 + mt * 16 + lq * 4;
                float4 bb = *(const float4*)(b2 + c0);
#pragma unroll
                for (int nt = 0; nt < 2; nt++) {
                    sv[mt][nt].x = swish_f(acc[mt][nt][0] + bb.x);
                    sv[mt][nt].y = swish_f(acc[mt][nt][1] + bb.y);
                    sv[mt][nt].z = swish_f(acc[mt][nt][2] + bb.z);
                    sv[mt][nt].w = swish_f(acc[mt][nt][3] + bb.w);
                }
            }
        }
        LDS_BARRIER();   // done reading M -> buffer becomes S_t

        // ---- write S_t transposed [c][e] ----
#pragma unroll
        for (int mt = 0; mt < 2; mt++) {
            int c0 = wv * 32 + mt * 16 + lq * 4;
#pragma unroll
            for (int nt = 0; nt < 2; nt++) {
                int e = nt * 16 + lr;
                St[(c0 + 0) * EP2 + e] = sv[mt][nt].x;
                St[(c0 + 1) * EP2 + e] = sv[mt][nt].y;
                St[(c0 + 2) * EP2 + e] = sv[mt][nt].z;
                St[(c0 + 3) * EP2 + e] = sv[mt][nt].w;
            }
        }
        LDS_BARRIER();

        // ---- segmented reduce: 256 threads, 16-edge halves, LDS-atomic flushes ----
        {
            const int c = tid & 127;
            const int hf = tid >> 7;
            const int eb2 = hf * 16;
            float v[16];
            const float* row = St + c * EP2 + eb2;
#pragma unroll
            for (int q = 0; q < 4; q++) *(float4*)&v[q * 4] = *(const float4*)&row[q * 4];
            int cur = s_dlm[cs][eb2];
            float a = v[0];
#pragma unroll
            for (int i = 1; i < 16; i++) {
                int dn = s_dlm[cs][eb2 + i];
                if (dn != cur) {
                    if (cur >= 0) atomicAdd(&Acc[cur * 128 + c], a);
                    a = v[i];
                    cur = dn;
                } else {
                    a += v[i];
                }
            }
            if (cur >= 0) atomicAdd(&Acc[cur * 128 + c], a);
        }
        LDS_BARRIER();   // scan done before next chunk overwrites MB/meta
    }

    // ---- epilogue: coalesced agg stores (exclusive ownership, no memset needed) ----
    {
        float4* ag = (float4*)(agg + (size_t)n0 * 128);
        const float4* as = (const float4*)Acc;
        ag[tid] = as[tid];
        ag[tid + 256] = as[tid + 256];
    }
}

// ---------------- Node MLP (MFMA, single LDS buffer, 4 blocks/CU) ----------------
__global__ __launch_bounds__(256, 4) void node_mlp_mfma(
    float* __restrict__ x, short* __restrict__ xb, const float* __restrict__ agg,
    const short* __restrict__ W1T, const float* __restrict__ b1,
    const short* __restrict__ W2T, const float* __restrict__ b2) {
    __shared__ __align__(16) short X[64 * MP];
    const int tid = threadIdx.x;
    const int n0 = blockIdx.x * 64;
    const int wv = tid >> 6;
    const int ln = tid & 63;
    const int lr = ln & 15;
    const int lq = ln >> 4;

    {
        int row = tid >> 2, p = tid & 3;
        int gn = n0 + row;
        if (gn < N_NODES) {
            const int4* xp = (const int4*)(xb + (size_t)gn * 128);
#pragma unroll
            for (int q = 0; q < 4; q++) {
                int c = p * 4 + q;
                *(int4*)(X + row * MP + c * 8) = xp[c];
            }
            const float4* ap = (const float4*)(agg + (size_t)gn * 128);
#pragma unroll
            for (int q = 0; q < 4; q++) {
                float4 f0 = ap[p * 8 + q * 2];
                float4 f1 = ap[p * 8 + q * 2 + 1];
                bh8 s;
                s[0] = f2bf(f0.x); s[1] = f2bf(f0.y); s[2] = f2bf(f0.z); s[3] = f2bf(f0.w);
                s[4] = f2bf(f1.x); s[5] = f2bf(f1.y); s[6] = f2bf(f1.z); s[7] = f2bf(f1.w);
                *(bh8*)(X + row * MP + 128 + p * 32 + q * 8) = s;
            }
        } else {
            int4 z4 = make_int4(0, 0, 0, 0);
#pragma unroll
            for (int q = 0; q < 8; q++) *(int4*)(X + row * MP + (p * 8 + q) * 8) = z4;
        }
    }
    __syncthreads();

    bh4 hv[4][4];
    {
        f32x4 acc[4][4];
#pragma unroll
        for (int a = 0; a < 4; a++)
#pragma unroll
            for (int b = 0; b < 4; b++) acc[a][b] = (f32x4)(0.f);

        const short* a_base = W1T + (size_t)(wv * 64 + lr) * 256 + lq * 8;
        for (int ks = 0; ks < 256; ks += 32) {
            bh8 af[4], bf[4];
#pragma unroll
            for (int mt = 0; mt < 4; mt++) af[mt] = *(const bh8*)(a_base + mt * 16 * 256 + ks);
#pragma unroll
            for (int nt = 0; nt < 4; nt++)
                bf[nt] = *(const bh8*)(X + (nt * 16 + lr) * MP + ks + lq * 8);
#pragma unroll
            for (int mt = 0; mt < 4; mt++)
#pragma unroll
                for (int nt = 0; nt < 4; nt++)
                    acc[mt][nt] = __builtin_amdgcn_mfma_f32_16x16x32_bf16(af[mt], bf[nt],
                                                                          acc[mt][nt], 0, 0, 0);
        }
#pragma unroll
        for (int mt = 0; mt < 4; mt++) {
            int h0 = wv * 64 + mt * 16 + lq * 4;
            float4 bb = *(const float4*)(b1 + h0);
#pragma unroll
            for (int nt = 0; nt < 4; nt++) {
                hv[mt][nt][0] = f2bf(swish_f(acc[mt][nt][0] + bb.x));
                hv[mt][nt][1] = f2bf(swish_f(acc[mt][nt][1] + bb.y));
                hv[mt][nt][2] = f2bf(swish_f(acc[mt][nt][2] + bb.z));
                hv[mt][nt][3] = f2bf(swish_f(acc[mt][nt][3] + bb.w));
            }
        }
    }
    __syncthreads();   // done reading A -> buffer becomes H

#pragma unroll
    for (int mt = 0; mt < 4; mt++) {
        int h0 = wv * 64 + mt * 16 + lq * 4;
#pragma unroll
        for (int nt = 0; nt < 4; nt++) {
            int e = nt * 16 + lr;
            *(bh4*)(X + e * MP + h0) = hv[mt][nt];
        }
    }
    __syncthreads();

    {
        f32x4 acc[2][4];
#pragma unroll
        for (int a = 0; a < 2; a++)
#pragma unroll
            for (int b = 0; b < 4; b++) acc[a][b] = (f32x4)(0.f);

        const short* a_base = W2T + (size_t)(wv * 32 + lr) * 256 + lq * 8;
        for (int ks = 0; ks < 256; ks += 32) {
            bh8 af[2], bf[4];
#pragma unroll
            for (int mt = 0; mt < 2; mt++) af[mt] = *(const bh8*)(a_base + mt * 16 * 256 + ks);
#pragma unroll
            for (int nt = 0; nt < 4; nt++)
                bf[nt] = *(const bh8*)(X + (nt * 16 + lr) * MP + ks + lq * 8);
#pragma unroll
            for (int mt = 0; mt < 2; mt++)
#pragma unroll
                for (int nt = 0; nt < 4; nt++)
                    acc[mt][nt] = __builtin_amdgcn_mfma_f32_16x16x32_bf16(af[mt], bf[nt],
                                                                          acc[mt][nt], 0, 0, 0);
        }
#pragma unroll
        for (int mt = 0; mt < 2; mt++) {
            int c0 = wv * 32 + mt * 16 + lq * 4;
            float4 bb = *(const float4*)(b2 + c0);
#pragma unroll
            for (int nt = 0; nt < 4; nt++) {
                int nl = nt * 16 + lr;
                int gn = n0 + nl;
                if (gn < N_NODES) {
                    float4 xv = *(const float4*)(x + (size_t)gn * 128 + c0);
                    float4 nv;
                    nv.x = xv.x + acc[mt][nt][0] + bb.x;
                    nv.y = xv.y + acc[mt][nt][1] + bb.y;
                    nv.z = xv.z + acc[mt][nt][2] + bb.z;
                    nv.w = xv.w + acc[mt][nt][3] + bb.w;
                    *(float4*)(x + (size_t)gn * 128 + c0) = nv;
                    bh4 pk;
                    pk[0] = f2bf(nv.x); pk[1] = f2bf(nv.y); pk[2] = f2bf(nv.z); pk[3] = f2bf(nv.w);
                    *(bh4*)(xb + (size_t)gn * 128 + c0) = pk;
                }
            }
        }
    }
}

// ---------------- Output head, atomic-free 3-stage ----------------
__global__ __launch_bounds__(256, 4) void out_stage1(
    const float* __restrict__ x, const float* __restrict__ w1, const float* __restrict__ b1,
    const float* __restrict__ w2, const float* __restrict__ b2, float* __restrict__ sval) {
    __shared__ float xr[32][128];
    __shared__ float red[4][32];
    const int tid = threadIdx.x;
    const int n0 = blockIdx.x * 32;

    {
        const float4* xs = (const float4*)(x + (size_t)n0 * 128);
        if (n0 + 32 <= N_NODES) {
#pragma unroll
            for (int q = 0; q < 4; q++) {
                int i = tid + q * 256;
                ((float4*)xr)[i] = xs[i];
            }
        } else {
#pragma unroll
            for (int q = 0; q < 4; q++) {
                int i = tid + q * 256;
                int nn = i >> 5;
                ((float4*)xr)[i] = (n0 + nn < N_NODES) ? xs[i] : make_float4(0.f, 0.f, 0.f, 0.f);
            }
        }
    }
    __syncthreads();

    float acc[32];
#pragma unroll
    for (int nn = 0; nn < 32; nn++) acc[nn] = 0.f;

    for (int k = 0; k < 128; k += 4) {
        float w_[4];
#pragma unroll
        for (int kk = 0; kk < 4; kk++) w_[kk] = w1[(size_t)(k + kk) * 256 + tid];
#pragma unroll
        for (int nn = 0; nn < 32; nn++) {
            float4 xv = *(const float4*)&xr[nn][k];
            acc[nn] += xv.x * w_[0] + xv.y * w_[1] + xv.z * w_[2] + xv.w * w_[3];
        }
    }

    const float bb = b1[tid];
    const float wc = w2[tid];
    const int lane = tid & 63, wvi = tid >> 6;
#pragma unroll
    for (int nn = 0; nn < 32; nn++) {
        float v = swish_f(acc[nn] + bb) * wc;
#pragma unroll
        for (int off = 32; off > 0; off >>= 1) v += __shfl_down(v, off, 64);
        if (lane == 0) red[wvi][nn] = v;
    }
    __syncthreads();
    if (tid < 32) {
        int gn = n0 + tid;
        if (gn < N_NODES)
            sval[gn] = red[0][tid] + red[1][tid] + red[2][tid] + red[3][tid] + b2[0];
    }
}

__global__ void out_stage2(const float* __restrict__ sval, const int* __restrict__ batch,
                           float* __restrict__ partial) {
    __shared__ float part[N_GRAPHS];
    const int tid = threadIdx.x;
    if (tid < N_GRAPHS) part[tid] = 0.f;
    __syncthreads();
    const int per_block = (N_NODES + OB2 - 1) / OB2;
    const int start = blockIdx.x * per_block;
    const int end = min(start + per_block, N_NODES);
    const int per_thread = (per_block + 255) / 256;
    int s = start + tid * per_thread;
    int e = min(s + per_thread, end);
    if (s < e) {
        int g = batch[s];
        float a = sval[s];
        for (int n = s + 1; n < e; n++) {
            int gg = batch[n];
            float v = sval[n];
            if (gg != g) {
                atomicAdd(&part[g], a);
                a = v;
                g = gg;
            } else {
                a += v;
            }
        }
        atomicAdd(&part[g], a);
    }
    __syncthreads();
    if (tid < N_GRAPHS) partial[blockIdx.x * N_GRAPHS + tid] = part[tid];
}

__global__ void out_stage3(const float* __restrict__ partial, float* __restrict__ out) {
    int g = threadIdx.x;
    if (g >= N_GRAPHS) return;
    float s = 0.f;
    for (int b = 0; b < OB2; b++) s += partial[b * N_GRAPHS + g];
    out[g] = s;
}

extern "C" void kernel_launch(void* const* d_in, const int* in_sizes, int n_in,
                              void* d_out, int out_size, void* d_ws, size_t ws_size,
                              hipStream_t stream) {
    const float* positions = (const float*)d_in[0];
    const float* edge_shift = (const float*)d_in[1];
    const float* lattice = (const float*)d_in[2];
    const int* atomic_numbers = (const int*)d_in[3];
    const int* edge_index = (const int*)d_in[4];
    const int* batch = (const int*)d_in[5];
    const float* embed_w = (const float*)d_in[6];
    const float* edge_w1 = (const float*)d_in[7];
    const float* edge_b1 = (const float*)d_in[8];
    const float* edge_w2 = (const float*)d_in[9];
    const float* edge_b2 = (const float*)d_in[10];
    const float* node_w1 = (const float*)d_in[11];
    const float* node_b1 = (const float*)d_in[12];
    const float* node_w2 = (const float*)d_in[13];
    const float* node_b2 = (const float*)d_in[14];
    const float* out_w1 = (const float*)d_in[15];
    const float* out_b1 = (const float*)d_in[16];
    const float* out_w2 = (const float*)d_in[17];
    const float* out_b2 = (const float*)d_in[18];

    // workspace layout (every piece 16B-aligned; ~134 MB total)
    float* ws = (float*)d_ws;
    float* x = ws;                                   // N*128 f32
    float* agg = x + (size_t)N_NODES * 128;          // N*128 f32
    float* d2 = agg + (size_t)N_NODES * 128;         // E f32
    short* xb = (short*)(d2 + N_EDGES);              // N*128 bf16
    short* ydb = xb + (size_t)N_NODES * 128;         // N*256 bf16
    short* ysb = ydb + (size_t)N_NODES * 256;        // N*256 bf16
    short* WcT = ysb + (size_t)N_NODES * 256;        // 3*512*128 bf16
    short* eW2T = WcT + 3 * 512 * 128;               // 3*128*256
    short* nW1T = eW2T + 3 * 128 * 256;              // 3*256*256
    short* nW2T = nW1T + 3 * 256 * 256;              // 3*128*256
    int* deg = (int*)(nW2T + 3 * 128 * 256);         // N
    int* fillc = deg + N_NODES;                      // N
    int* sc = fillc + N_NODES;                       // N
    int* bsum = sc + N_NODES;                        // 128
    int4* epack = (int4*)(bsum + 128);               // E * 16B (dst-sorted src,dst,d2)
    int* rowptr = (int*)(epack + N_EDGES);           // N+1
    float* sval = (float*)(rowptr + N_NODES + 4);    // N
    float* partial = sval + N_NODES;                 // OB2*N_GRAPHS

    (void)hipMemsetAsync(deg, 0, N_NODES * sizeof(int), stream);
    (void)hipMemsetAsync(fillc, 0, N_NODES * sizeof(int), stream);

    // weight transpose+cvt (tiny)
    {
        int tc = 3 * 512 * 128;
        cvt_wc_kernel<<<(tc + 255) / 256, 256, 0, stream>>>(edge_w1, WcT, tc);
        int t2 = 3 * 128 * 256;
        cvt_wT_kernel<<<(t2 + 255) / 256, 256, 0, stream>>>(edge_w2, eW2T, 256, 128, 256, t2);
        int t3 = 3 * 256 * 256;
        cvt_wT_kernel<<<(t3 + 255) / 256, 256, 0, stream>>>(node_w1, nW1T, 256, 256, 256, t3);
        cvt_wT_kernel<<<(t2 + 255) / 256, 256, 0, stream>>>(node_w2, nW2T, 256, 128, 256, t2);
    }

    prep_kernel<<<(N_EDGES + 255) / 256, 256, 0, stream>>>(positions, edge_shift, lattice,
                                                           edge_index, batch, d2);
    embed_kernel<<<(N_NODES * 128) / 256, 256, 0, stream>>>(embed_w, atomic_numbers, x, xb);

    // CSR counting sort by dst (packs src,dst,d2 per edge)
    {
        int nscan = (N_NODES + SCAN_BS - 1) / SCAN_BS;
        hist_kernel<<<(N_EDGES + 255) / 256, 256, 0, stream>>>(edge_index, deg);
        scan1_kernel<<<nscan, SCAN_BS, 0, stream>>>(deg, sc, bsum, N_NODES);
        scan2_kernel<<<1, 128, 0, stream>>>(bsum, nscan);
        scan3_kernel<<<(N_NODES + SCAN_BS) / SCAN_BS + 1, SCAN_BS, 0, stream>>>(
            sc, deg, bsum, rowptr, N_NODES, N_EDGES);
        fill_kernel<<<(N_EDGES + 255) / 256, 256, 0, stream>>>(edge_index, d2, rowptr, fillc,
                                                               epack);
    }

    const int nblk = (N_NODES + 63) / 64;
    for (int l = 0; l < N_LAYERS; l++) {
        y_precompute<<<nblk * 2, 256, 0, stream>>>(
            xb, WcT + (size_t)l * 512 * 128, edge_b1 + (size_t)l * 256, ydb, ysb);
        edge_mlp_csr<<<N_NODES / DQ, 256, 0, stream>>>(
            ydb, ysb, edge_w1 + ((size_t)l * 257 + 256) * 256, epack, rowptr,
            eW2T + (size_t)l * 128 * 256, edge_b2 + (size_t)l * 128, agg);
        node_mlp_mfma<<<nblk, 256, 0, stream>>>(
            x, xb, agg,
            nW1T + (size_t)l * 256 * 256, node_b1 + (size_t)l * 256,
            nW2T + (size_t)l * 128 * 256, node_b2 + (size_t)l * 128);
    }
    out_stage1<<<(N_NODES + 31) / 32, 256, 0, stream>>>(x, out_w1, out_b1, out_w2, out_b2, sval);
    out_stage2<<<OB2, 256, 0, stream>>>(sval, batch, partial);
    out_stage3<<<1, 64, 0, stream>>>(partial, (float*)d_out);
}

// Round 8
// 1161.075 us; speedup vs baseline: 1.5109x; 1.5109x over previous
//
#include <hip/hip_runtime.h>
#include <hip/hip_bf16.h>

#define N_NODES 50000
#define N_EDGES 800000
#define N_GRAPHS 32
#define NODE_DIM 128
#define HIDDEN 256
#define N_LAYERS 3

typedef __attribute__((ext_vector_type(8))) short bh8;   // 8 bf16 (4 VGPRs)
typedef __attribute__((ext_vector_type(4))) short bh4;   // 4 bf16 (8B)
typedef __attribute__((ext_vector_type(4))) float f32x4; // MFMA acc

#define MP 264  // M/H tile pitch (bf16)
#define YP 136  // y_precompute X-tile pitch (bf16)
#define DQ 16   // dst nodes per edge-CSR block
#define EP2 36  // St pitch (fp32): 36%32=4
#define YDP 264 // ydc LDS pitch (shorts)
#define WSP 36  // wsh pitch (floats): 8 groups at distinct banks, 16B-aligned
#define SCAN_BS 512
#define OB2 32  // out_stage2 blocks

// swish via hw rcp (avoids full-precision fp32 divide sequence)
__device__ __forceinline__ float swish_f(float v) {
    return v * __builtin_amdgcn_rcpf(1.0f + __expf(-v));
}

// round-half-up bf16 (2 int ops; differs from RNE only on exact ties)
__device__ __forceinline__ short f2bf(float f) {
    union { float f; unsigned u; } v;
    v.f = f;
    return (short)((v.u + 0x8000u) >> 16);
}

__device__ __forceinline__ float bf2f(short s) {
    union { unsigned u; float f; } v;
    v.u = ((unsigned)(unsigned short)s) << 16;
    return v.f;
}

// d2[e] = |pos[dst] - pos[src] + shift @ lattice[batch[src]]|^2
__global__ void prep_kernel(const float* __restrict__ pos, const float* __restrict__ shift,
                            const float* __restrict__ lattice, const int* __restrict__ eidx,
                            const int* __restrict__ batch, float* __restrict__ d2) {
    int e = blockIdx.x * blockDim.x + threadIdx.x;
    if (e >= N_EDGES) return;
    int s = eidx[e];
    int d = eidx[N_EDGES + e];
    int b = batch[s];
    const float* lat = lattice + b * 9;
    float s0 = shift[e * 3 + 0], s1 = shift[e * 3 + 1], s2 = shift[e * 3 + 2];
    float acc = 0.f;
#pragma unroll
    for (int j = 0; j < 3; j++) {
        float v = pos[d * 3 + j] - pos[s * 3 + j] + s0 * lat[j] + s1 * lat[3 + j] + s2 * lat[6 + j];
        acc += v * v;
    }
    d2[e] = acc;
}

// x[n][c] = embed[z[n]][c]; also bf16 mirror
__global__ void embed_kernel(const float* __restrict__ emb, const int* __restrict__ z,
                             float* __restrict__ x, short* __restrict__ xb) {
    int i = blockIdx.x * blockDim.x + threadIdx.x;
    int n = i >> 7, c = i & 127;
    float v = emb[z[n] * 128 + c];
    x[i] = v;
    xb[i] = f2bf(v);
}

// out[l][h][k] = bf16(in[l][k][h]) for k<K_in else 0
__global__ void cvt_wT_kernel(const float* __restrict__ in, short* __restrict__ out,
                              int K_in, int H, int K_pad, int total) {
    int i = blockIdx.x * blockDim.x + threadIdx.x;
    if (i >= total) return;
    int k = i % K_pad;
    int t = i / K_pad;
    int h = t % H;
    int l = t / H;
    out[i] = (k < K_in) ? f2bf(in[((size_t)l * K_in + k) * H + h]) : (short)0;
}

// combined edge-W1 transpose: out[l][m][k] bf16, m<256 -> W1[l][k][m] (dst part),
// m>=256 -> W1[l][128+k][m-256] (src part). K=128 exact.
__global__ void cvt_wc_kernel(const float* __restrict__ in, short* __restrict__ out, int total) {
    int i = blockIdx.x * blockDim.x + threadIdx.x;
    if (i >= total) return;
    int k = i & 127;
    int t = i >> 7;
    int m = t & 511;
    int l = t >> 9;
    size_t src;
    if (m < 256) src = ((size_t)l * 257 + k) * 256 + m;
    else src = ((size_t)l * 257 + 128 + k) * 256 + (m - 256);
    out[i] = f2bf(in[src]);
}

// ---- CSR counting-sort build ----
__global__ void hist_kernel(const int* __restrict__ eidx, int* __restrict__ deg) {
    int e = blockIdx.x * blockDim.x + threadIdx.x;
    if (e >= N_EDGES) return;
    atomicAdd(&deg[eidx[N_EDGES + e]], 1);
}

__global__ void scan1_kernel(const int* __restrict__ deg, int* __restrict__ sc,
                             int* __restrict__ bsum, int n) {
    __shared__ int s[SCAN_BS];
    int i = blockIdx.x * SCAN_BS + threadIdx.x;
    int v = (i < n) ? deg[i] : 0;
    s[threadIdx.x] = v;
    __syncthreads();
    for (int off = 1; off < SCAN_BS; off <<= 1) {
        int t = (threadIdx.x >= off) ? s[threadIdx.x - off] : 0;
        __syncthreads();
        s[threadIdx.x] += t;
        __syncthreads();
    }
    if (i < n) sc[i] = s[threadIdx.x];
    if (threadIdx.x == SCAN_BS - 1) bsum[blockIdx.x] = s[SCAN_BS - 1];
}

__global__ void scan2_kernel(int* __restrict__ bsum, int nb) {  // 1 block, 128 threads
    __shared__ int s[128];
    int v = (threadIdx.x < nb) ? bsum[threadIdx.x] : 0;
    s[threadIdx.x] = v;
    __syncthreads();
    for (int off = 1; off < 128; off <<= 1) {
        int t = (threadIdx.x >= off) ? s[threadIdx.x - off] : 0;
        __syncthreads();
        s[threadIdx.x] += t;
        __syncthreads();
    }
    if (threadIdx.x < nb) bsum[threadIdx.x] = s[threadIdx.x];
}

__global__ void scan3_kernel(const int* __restrict__ sc, const int* __restrict__ deg,
                             const int* __restrict__ bsum, int* __restrict__ rowptr,
                             int n, int total) {
    int i = blockIdx.x * SCAN_BS + threadIdx.x;
    if (i > n) return;
    if (i == n) { rowptr[n] = total; return; }
    int off = (blockIdx.x > 0) ? bsum[blockIdx.x - 1] : 0;
    rowptr[i] = sc[i] - deg[i] + off;
}

// scatter into dst-sorted order, packing (src, dst, d2)
__global__ void fill_kernel(const int* __restrict__ eidx, const float* __restrict__ d2,
                            const int* __restrict__ rowptr, int* __restrict__ fillc,
                            int4* __restrict__ epack) {
    int e = blockIdx.x * blockDim.x + threadIdx.x;
    if (e >= N_EDGES) return;
    int s = eidx[e];
    int d = eidx[N_EDGES + e];
    int p = rowptr[d] + atomicAdd(&fillc[d], 1);
    epack[p] = make_int4(s, d, __float_as_int(d2[e]), 0);
}

// ---------------- per-layer node-level GEMM1 precompute ----------------
__global__ __launch_bounds__(256, 4) void y_precompute(
    const short* __restrict__ xb, const short* __restrict__ WcT,
    const float* __restrict__ b1, short* __restrict__ ydb, short* __restrict__ ysb) {
    __shared__ __align__(16) short B[64 * MP];  // X [64][YP] then Y [64][MP]
    const int tid = threadIdx.x;
    const int half = blockIdx.x & 1;
    const int n0 = (blockIdx.x >> 1) * 64;
    const int wv = tid >> 6;
    const int ln = tid & 63;
    const int lr = ln & 15;
    const int lq = ln >> 4;

    {
        int row = tid >> 2, p = tid & 3;
        int gn = n0 + row;
        if (gn < N_NODES) {
            const int4* xp = (const int4*)(xb + (size_t)gn * 128) + p * 4;
#pragma unroll
            for (int i = 0; i < 4; i++) *(int4*)(B + row * YP + (p * 4 + i) * 8) = xp[i];
        } else {
            int4 z4 = make_int4(0, 0, 0, 0);
#pragma unroll
            for (int i = 0; i < 4; i++) *(int4*)(B + row * YP + (p * 4 + i) * 8) = z4;
        }
    }
    __syncthreads();

    f32x4 acc[4][4];
#pragma unroll
    for (int a = 0; a < 4; a++)
#pragma unroll
        for (int b = 0; b < 4; b++) acc[a][b] = (f32x4)(0.f);

    const short* a_base = WcT + (size_t)(half * 256 + wv * 64 + lr) * 128 + lq * 8;
#pragma unroll
    for (int ks = 0; ks < 128; ks += 32) {
        bh8 af[4], bf[4];
#pragma unroll
        for (int mt = 0; mt < 4; mt++) af[mt] = *(const bh8*)(a_base + mt * 16 * 128 + ks);
#pragma unroll
        for (int nt = 0; nt < 4; nt++)
            bf[nt] = *(const bh8*)(B + (nt * 16 + lr) * YP + ks + lq * 8);
#pragma unroll
        for (int mt = 0; mt < 4; mt++)
#pragma unroll
            for (int nt = 0; nt < 4; nt++)
                acc[mt][nt] = __builtin_amdgcn_mfma_f32_16x16x32_bf16(af[mt], bf[nt],
                                                                      acc[mt][nt], 0, 0, 0);
    }
    __syncthreads();   // done reading X -> B becomes Y [64][MP]

#pragma unroll
    for (int mt = 0; mt < 4; mt++) {
        int h0 = wv * 64 + mt * 16 + lq * 4;
        float4 bb = half ? make_float4(0.f, 0.f, 0.f, 0.f) : *(const float4*)(b1 + h0);
#pragma unroll
        for (int nt = 0; nt < 4; nt++) {
            bh4 pk;
            pk[0] = f2bf(acc[mt][nt][0] + bb.x);
            pk[1] = f2bf(acc[mt][nt][1] + bb.y);
            pk[2] = f2bf(acc[mt][nt][2] + bb.z);
            pk[3] = f2bf(acc[mt][nt][3] + bb.w);
            *(bh4*)(B + (nt * 16 + lr) * MP + h0) = pk;
        }
    }
    __syncthreads();

    // coalesced copy: instr i writes 64 consecutive int4 (1KB contiguous)
    short* outp = half ? ysb : ydb;
    int4* og = (int4*)(outp + (size_t)n0 * 256);
#pragma unroll
    for (int i = 0; i < 8; i++) {
        int f = i * 256 + tid;             // flat int4 index over [64][256]
        int row = f >> 5;
        if (n0 + row < N_NODES)
            og[f] = *(const int4*)(B + row * MP + (f & 31) * 8);
    }
}

// ---------------- Edge MLP, CSR dst-centric (r4 structure, spill-free) ----------------
// Block owns DQ=16 dst nodes (contiguous edge range in dst-sorted epack).
// yd rows staged in LDS once (16x reuse); w1c staged in LDS (wsh) — this was the
// r4 spill source (wreg[32] vs the 64-VGPR cap -> ~410MB scratch traffic/dispatch).
// Synchronous ys gather (L3-resident table); 4 blocks/CU provide cross-block
// latency overlap. Per-block f32 accumulator in LDS; no global atomics, no memset.
__global__ __launch_bounds__(256, 4) void edge_mlp_csr(
    const short* __restrict__ ydb, const short* __restrict__ ysb,
    const float* __restrict__ w1c,   // [256] f32: W1 row 256 (the d2 row)
    const int4* __restrict__ epack,  // dst-sorted (src, dst, d2)
    const int* __restrict__ rowptr,
    const short* __restrict__ W2T,   // [128][256] bf16
    const float* __restrict__ b2,
    float* __restrict__ agg) {
    __shared__ __align__(16) short MB[9216];        // 18432B: M [32][MP] / St [128][EP2] f32
    __shared__ __align__(16) short ydc[DQ * YDP];   // 8448B
    __shared__ __align__(16) float Acc[DQ * 128];   // 8192B
    __shared__ __align__(16) float wsh[8 * WSP];    // 1152B, [p][32] pitch 36
    __shared__ int s_dl[32];
    float* St = (float*)MB;
    const int tid = threadIdx.x;
    const int n0 = blockIdx.x * DQ;
    const int wv = tid >> 6;
    const int ln = tid & 63;
    const int lr = ln & 15;
    const int lq = ln >> 4;
    const int el = tid >> 3;
    const int p = tid & 7;

    const int estart = rowptr[n0];
    const int eend = rowptr[n0 + DQ];

    // ---- phase 0: stage yd rows (coalesced), zero Acc, w1c -> wsh ----
    {
        const int4* src = (const int4*)(ydb + (size_t)n0 * 256);  // 512 int4 contiguous
        int4* dst = (int4*)ydc;
#pragma unroll
        for (int i = 0; i < 2; i++) {
            int f = tid + i * 256;
            dst[(f >> 5) * 33 + (f & 31)] = src[f];   // YDP=264 shorts = 33 int4
        }
        float4* az = (float4*)Acc;
        az[tid] = make_float4(0.f, 0.f, 0.f, 0.f);
        az[tid + 256] = make_float4(0.f, 0.f, 0.f, 0.f);
        wsh[(tid >> 5) * WSP + (tid & 31)] = w1c[tid];
    }
    __syncthreads();

    const int nch = (eend - estart + 31) >> 5;
    for (int ch = 0; ch < nch; ch++) {
        const int e0 = estart + ch * 32;

        // ---- stage A: gather ys[src] + ydc[dl] + d2*wsh -> swish -> M (8 thr/edge) ----
        {
            int e = e0 + el;
            bool valid = e < eend;
            int s = 0, dl = -1;
            float d2v = 0.f;
            if (valid) {
                int4 ep = epack[e];
                s = ep.x;
                dl = ep.y - n0;
                d2v = __int_as_float(ep.z);
            }
            if (p == 0) s_dl[el] = dl;
            if (valid) {
                const int4* ys = (const int4*)(ysb + (size_t)s * 256) + p * 4;
                int4 bv[4];
#pragma unroll
                for (int q = 0; q < 4; q++) bv[q] = ys[q];
                const short* yl = ydc + dl * YDP + p * 32;
                const float* wl = wsh + p * WSP;
#pragma unroll
                for (int q = 0; q < 4; q++) {
                    union { int4 v; short s2[8]; } b, m;
                    b.v = bv[q];
                    bh8 av = *(const bh8*)(yl + q * 8);
                    float4 w0 = *(const float4*)(wl + q * 8);
                    float4 w1 = *(const float4*)(wl + q * 8 + 4);
                    float wf[8] = {w0.x, w0.y, w0.z, w0.w, w1.x, w1.y, w1.z, w1.w};
#pragma unroll
                    for (int j = 0; j < 8; j++) {
                        float f = bf2f(av[j]) + bf2f(b.s2[j]) + d2v * wf[j];
                        m.s2[j] = f2bf(swish_f(f));
                    }
                    *(int4*)(MB + el * MP + p * 32 + q * 8) = m.v;
                }
            } else {
                int4 z4 = make_int4(0, 0, 0, 0);
#pragma unroll
                for (int q = 0; q < 4; q++) *(int4*)(MB + el * MP + p * 32 + q * 8) = z4;
            }
        }
        __syncthreads();

        // ---- GEMM2: 128 ch x 32 edges, each wave 32 ch ----
        float4 sv[2][2];
        {
            f32x4 acc[2][2];
#pragma unroll
            for (int a = 0; a < 2; a++)
#pragma unroll
                for (int b = 0; b < 2; b++) acc[a][b] = (f32x4)(0.f);

            const short* a_base = W2T + (size_t)(wv * 32 + lr) * 256 + lq * 8;
            for (int ks = 0; ks < 256; ks += 32) {
                bh8 af[2], bf[2];
#pragma unroll
                for (int mt = 0; mt < 2; mt++) af[mt] = *(const bh8*)(a_base + mt * 16 * 256 + ks);
#pragma unroll
                for (int nt = 0; nt < 2; nt++)
                    bf[nt] = *(const bh8*)(MB + (nt * 16 + lr) * MP + ks + lq * 8);
#pragma unroll
                for (int mt = 0; mt < 2; mt++)
#pragma unroll
                    for (int nt = 0; nt < 2; nt++)
                        acc[mt][nt] = __builtin_amdgcn_mfma_f32_16x16x32_bf16(af[mt], bf[nt],
                                                                              acc[mt][nt], 0, 0, 0);
            }
#pragma unroll
            for (int mt = 0; mt < 2; mt++) {
                int c0 = wv * 32 + mt * 16 + lq * 4;
                float4 bb = *(const float4*)(b2 + c0);
#pragma unroll
                for (int nt = 0; nt < 2; nt++) {
                    sv[mt][nt].x = swish_f(acc[mt][nt][0] + bb.x);
                    sv[mt][nt].y = swish_f(acc[mt][nt][1] + bb.y);
                    sv[mt][nt].z = swish_f(acc[mt][nt][2] + bb.z);
                    sv[mt][nt].w = swish_f(acc[mt][nt][3] + bb.w);
                }
            }
        }
        __syncthreads();   // done reading M -> buffer becomes S_t

        // ---- write S_t transposed [c][e] ----
#pragma unroll
        for (int mt = 0; mt < 2; mt++) {
            int c0 = wv * 32 + mt * 16 + lq * 4;
#pragma unroll
            for (int nt = 0; nt < 2; nt++) {
                int e = nt * 16 + lr;
                St[(c0 + 0) * EP2 + e] = sv[mt][nt].x;
                St[(c0 + 1) * EP2 + e] = sv[mt][nt].y;
                St[(c0 + 2) * EP2 + e] = sv[mt][nt].z;
                St[(c0 + 3) * EP2 + e] = sv[mt][nt].w;
            }
        }
        __syncthreads();

        // ---- segmented reduce: 256 threads, 16-edge halves, LDS-atomic flushes ----
        {
            const int c = tid & 127;
            const int hf = tid >> 7;
            const int eb2 = hf * 16;
            float v[16];
            const float* row = St + c * EP2 + eb2;
#pragma unroll
            for (int q = 0; q < 4; q++) *(float4*)&v[q * 4] = *(const float4*)&row[q * 4];
            int cur = s_dl[eb2];
            float a = v[0];
#pragma unroll
            for (int i = 1; i < 16; i++) {
                int dn = s_dl[eb2 + i];
                if (dn != cur) {
                    if (cur >= 0) atomicAdd(&Acc[cur * 128 + c], a);
                    a = v[i];
                    cur = dn;
                } else {
                    a += v[i];
                }
            }
            if (cur >= 0) atomicAdd(&Acc[cur * 128 + c], a);
        }
        __syncthreads();   // scan done before next chunk overwrites MB/s_dl
    }

    // ---- epilogue: coalesced agg stores (exclusive ownership, no memset needed) ----
    {
        float4* ag = (float4*)(agg + (size_t)n0 * 128);
        const float4* as = (const float4*)Acc;
        ag[tid] = as[tid];
        ag[tid + 256] = as[tid + 256];
    }
}

// ---------------- Node MLP (MFMA, single LDS buffer, 4 blocks/CU) ----------------
__global__ __launch_bounds__(256, 4) void node_mlp_mfma(
    float* __restrict__ x, short* __restrict__ xb, const float* __restrict__ agg,
    const short* __restrict__ W1T, const float* __restrict__ b1,
    const short* __restrict__ W2T, const float* __restrict__ b2) {
    __shared__ __align__(16) short X[64 * MP];
    const int tid = threadIdx.x;
    const int n0 = blockIdx.x * 64;
    const int wv = tid >> 6;
    const int ln = tid & 63;
    const int lr = ln & 15;
    const int lq = ln >> 4;

    {
        int row = tid >> 2, p = tid & 3;
        int gn = n0 + row;
        if (gn < N_NODES) {
            const int4* xp = (const int4*)(xb + (size_t)gn * 128);
#pragma unroll
            for (int q = 0; q < 4; q++) {
                int c = p * 4 + q;
                *(int4*)(X + row * MP + c * 8) = xp[c];
            }
            const float4* ap = (const float4*)(agg + (size_t)gn * 128);
#pragma unroll
            for (int q = 0; q < 4; q++) {
                float4 f0 = ap[p * 8 + q * 2];
                float4 f1 = ap[p * 8 + q * 2 + 1];
                bh8 s;
                s[0] = f2bf(f0.x); s[1] = f2bf(f0.y); s[2] = f2bf(f0.z); s[3] = f2bf(f0.w);
                s[4] = f2bf(f1.x); s[5] = f2bf(f1.y); s[6] = f2bf(f1.z); s[7] = f2bf(f1.w);
                *(bh8*)(X + row * MP + 128 + p * 32 + q * 8) = s;
            }
        } else {
            int4 z4 = make_int4(0, 0, 0, 0);
#pragma unroll
            for (int q = 0; q < 8; q++) *(int4*)(X + row * MP + (p * 8 + q) * 8) = z4;
        }
    }
    __syncthreads();

    bh4 hv[4][4];
    {
        f32x4 acc[4][4];
#pragma unroll
        for (int a = 0; a < 4; a++)
#pragma unroll
            for (int b = 0; b < 4; b++) acc[a][b] = (f32x4)(0.f);

        const short* a_base = W1T + (size_t)(wv * 64 + lr) * 256 + lq * 8;
        for (int ks = 0; ks < 256; ks += 32) {
            bh8 af[4], bf[4];
#pragma unroll
            for (int mt = 0; mt < 4; mt++) af[mt] = *(const bh8*)(a_base + mt * 16 * 256 + ks);
#pragma unroll
            for (int nt = 0; nt < 4; nt++)
                bf[nt] = *(const bh8*)(X + (nt * 16 + lr) * MP + ks + lq * 8);
#pragma unroll
            for (int mt = 0; mt < 4; mt++)
#pragma unroll
                for (int nt = 0; nt < 4; nt++)
                    acc[mt][nt] = __builtin_amdgcn_mfma_f32_16x16x32_bf16(af[mt], bf[nt],
                                                                          acc[mt][nt], 0, 0, 0);
        }
#pragma unroll
        for (int mt = 0; mt < 4; mt++) {
            int h0 = wv * 64 + mt * 16 + lq * 4;
            float4 bb = *(const float4*)(b1 + h0);
#pragma unroll
            for (int nt = 0; nt < 4; nt++) {
                hv[mt][nt][0] = f2bf(swish_f(acc[mt][nt][0] + bb.x));
                hv[mt][nt][1] = f2bf(swish_f(acc[mt][nt][1] + bb.y));
                hv[mt][nt][2] = f2bf(swish_f(acc[mt][nt][2] + bb.z));
                hv[mt][nt][3] = f2bf(swish_f(acc[mt][nt][3] + bb.w));
            }
        }
    }
    __syncthreads();   // done reading A -> buffer becomes H

#pragma unroll
    for (int mt = 0; mt < 4; mt++) {
        int h0 = wv * 64 + mt * 16 + lq * 4;
#pragma unroll
        for (int nt = 0; nt < 4; nt++) {
            int e = nt * 16 + lr;
            *(bh4*)(X + e * MP + h0) = hv[mt][nt];
        }
    }
    __syncthreads();

    {
        f32x4 acc[2][4];
#pragma unroll
        for (int a = 0; a < 2; a++)
#pragma unroll
            for (int b = 0; b < 4; b++) acc[a][b] = (f32x4)(0.f);

        const short* a_base = W2T + (size_t)(wv * 32 + lr) * 256 + lq * 8;
        for (int ks = 0; ks < 256; ks += 32) {
            bh8 af[2], bf[4];
#pragma unroll
            for (int mt = 0; mt < 2; mt++) af[mt] = *(const bh8*)(a_base + mt * 16 * 256 + ks);
#pragma unroll
            for (int nt = 0; nt < 4; nt++)
                bf[nt] = *(const bh8*)(X + (nt * 16 + lr) * MP + ks + lq * 8);
#pragma unroll
            for (int mt = 0; mt < 2; mt++)
#pragma unroll
                for (int nt = 0; nt < 4; nt++)
                    acc[mt][nt] = __builtin_amdgcn_mfma_f32_16x16x32_bf16(af[mt], bf[nt],
                                                                          acc[mt][nt], 0, 0, 0);
        }
#pragma unroll
        for (int mt = 0; mt < 2; mt++) {
            int c0 = wv * 32 + mt * 16 + lq * 4;
            float4 bb = *(const float4*)(b2 + c0);
#pragma unroll
            for (int nt = 0; nt < 4; nt++) {
                int nl = nt * 16 + lr;
                int gn = n0 + nl;
                if (gn < N_NODES) {
                    float4 xv = *(const float4*)(x + (size_t)gn * 128 + c0);
                    float4 nv;
                    nv.x = xv.x + acc[mt][nt][0] + bb.x;
                    nv.y = xv.y + acc[mt][nt][1] + bb.y;
                    nv.z = xv.z + acc[mt][nt][2] + bb.z;
                    nv.w = xv.w + acc[mt][nt][3] + bb.w;
                    *(float4*)(x + (size_t)gn * 128 + c0) = nv;
                    bh4 pk;
                    pk[0] = f2bf(nv.x); pk[1] = f2bf(nv.y); pk[2] = f2bf(nv.z); pk[3] = f2bf(nv.w);
                    *(bh4*)(xb + (size_t)gn * 128 + c0) = pk;
                }
            }
        }
    }
}

// ---------------- Output head, atomic-free 3-stage ----------------
__global__ __launch_bounds__(256, 4) void out_stage1(
    const float* __restrict__ x, const float* __restrict__ w1, const float* __restrict__ b1,
    const float* __restrict__ w2, const float* __restrict__ b2, float* __restrict__ sval) {
    __shared__ float xr[32][128];
    __shared__ float red[4][32];
    const int tid = threadIdx.x;
    const int n0 = blockIdx.x * 32;

    {
        const float4* xs = (const float4*)(x + (size_t)n0 * 128);
        if (n0 + 32 <= N_NODES) {
#pragma unroll
            for (int q = 0; q < 4; q++) {
                int i = tid + q * 256;
                ((float4*)xr)[i] = xs[i];
            }
        } else {
#pragma unroll
            for (int q = 0; q < 4; q++) {
                int i = tid + q * 256;
                int nn = i >> 5;
                ((float4*)xr)[i] = (n0 + nn < N_NODES) ? xs[i] : make_float4(0.f, 0.f, 0.f, 0.f);
            }
        }
    }
    __syncthreads();

    float acc[32];
#pragma unroll
    for (int nn = 0; nn < 32; nn++) acc[nn] = 0.f;

    for (int k = 0; k < 128; k += 4) {
        float w_[4];
#pragma unroll
        for (int kk = 0; kk < 4; kk++) w_[kk] = w1[(size_t)(k + kk) * 256 + tid];
#pragma unroll
        for (int nn = 0; nn < 32; nn++) {
            float4 xv = *(const float4*)&xr[nn][k];
            acc[nn] += xv.x * w_[0] + xv.y * w_[1] + xv.z * w_[2] + xv.w * w_[3];
        }
    }

    const float bb = b1[tid];
    const float wc = w2[tid];
    const int lane = tid & 63, wvi = tid >> 6;
#pragma unroll
    for (int nn = 0; nn < 32; nn++) {
        float v = swish_f(acc[nn] + bb) * wc;
#pragma unroll
        for (int off = 32; off > 0; off >>= 1) v += __shfl_down(v, off, 64);
        if (lane == 0) red[wvi][nn] = v;
    }
    __syncthreads();
    if (tid < 32) {
        int gn = n0 + tid;
        if (gn < N_NODES)
            sval[gn] = red[0][tid] + red[1][tid] + red[2][tid] + red[3][tid] + b2[0];
    }
}

__global__ void out_stage2(const float* __restrict__ sval, const int* __restrict__ batch,
                           float* __restrict__ partial) {
    __shared__ float part[N_GRAPHS];
    const int tid = threadIdx.x;
    if (tid < N_GRAPHS) part[tid] = 0.f;
    __syncthreads();
    const int per_block = (N_NODES + OB2 - 1) / OB2;
    const int start = blockIdx.x * per_block;
    const int end = min(start + per_block, N_NODES);
    const int per_thread = (per_block + 255) / 256;
    int s = start + tid * per_thread;
    int e = min(s + per_thread, end);
    if (s < e) {
        int g = batch[s];
        float a = sval[s];
        for (int n = s + 1; n < e; n++) {
            int gg = batch[n];
            float v = sval[n];
            if (gg != g) {
                atomicAdd(&part[g], a);
                a = v;
                g = gg;
            } else {
                a += v;
            }
        }
        atomicAdd(&part[g], a);
    }
    __syncthreads();
    if (tid < N_GRAPHS) partial[blockIdx.x * N_GRAPHS + tid] = part[tid];
}

__global__ void out_stage3(const float* __restrict__ partial, float* __restrict__ out) {
    int g = threadIdx.x;
    if (g >= N_GRAPHS) return;
    float s = 0.f;
    for (int b = 0; b < OB2; b++) s += partial[b * N_GRAPHS + g];
    out[g] = s;
}

extern "C" void kernel_launch(void* const* d_in, const int* in_sizes, int n_in,
                              void* d_out, int out_size, void* d_ws, size_t ws_size,
                              hipStream_t stream) {
    const float* positions = (const float*)d_in[0];
    const float* edge_shift = (const float*)d_in[1];
    const float* lattice = (const float*)d_in[2];
    const int* atomic_numbers = (const int*)d_in[3];
    const int* edge_index = (const int*)d_in[4];
    const int* batch = (const int*)d_in[5];
    const float* embed_w = (const float*)d_in[6];
    const float* edge_w1 = (const float*)d_in[7];
    const float* edge_b1 = (const float*)d_in[8];
    const float* edge_w2 = (const float*)d_in[9];
    const float* edge_b2 = (const float*)d_in[10];
    const float* node_w1 = (const float*)d_in[11];
    const float* node_b1 = (const float*)d_in[12];
    const float* node_w2 = (const float*)d_in[13];
    const float* node_b2 = (const float*)d_in[14];
    const float* out_w1 = (const float*)d_in[15];
    const float* out_b1 = (const float*)d_in[16];
    const float* out_w2 = (const float*)d_in[17];
    const float* out_b2 = (const float*)d_in[18];

    // workspace layout (every piece 16B-aligned; ~134 MB total)
    float* ws = (float*)d_ws;
    float* x = ws;                                   // N*128 f32
    float* agg = x + (size_t)N_NODES * 128;          // N*128 f32
    float* d2 = agg + (size_t)N_NODES * 128;         // E f32
    short* xb = (short*)(d2 + N_EDGES);              // N*128 bf16
    short* ydb = xb + (size_t)N_NODES * 128;         // N*256 bf16
    short* ysb = ydb + (size_t)N_NODES * 256;        // N*256 bf16
    short* WcT = ysb + (size_t)N_NODES * 256;        // 3*512*128 bf16
    short* eW2T = WcT + 3 * 512 * 128;               // 3*128*256
    short* nW1T = eW2T + 3 * 128 * 256;              // 3*256*256
    short* nW2T = nW1T + 3 * 256 * 256;              // 3*128*256
    int* deg = (int*)(nW2T + 3 * 128 * 256);         // N
    int* fillc = deg + N_NODES;                      // N
    int* sc = fillc + N_NODES;                       // N
    int* bsum = sc + N_NODES;                        // 128
    int4* epack = (int4*)(bsum + 128);               // E * 16B (dst-sorted src,dst,d2)
    int* rowptr = (int*)(epack + N_EDGES);           // N+1
    float* sval = (float*)(rowptr + N_NODES + 4);    // N
    float* partial = sval + N_NODES;                 // OB2*N_GRAPHS

    (void)hipMemsetAsync(deg, 0, N_NODES * sizeof(int), stream);
    (void)hipMemsetAsync(fillc, 0, N_NODES * sizeof(int), stream);

    // weight transpose+cvt (tiny)
    {
        int tc = 3 * 512 * 128;
        cvt_wc_kernel<<<(tc + 255) / 256, 256, 0, stream>>>(edge_w1, WcT, tc);
        int t2 = 3 * 128 * 256;
        cvt_wT_kernel<<<(t2 + 255) / 256, 256, 0, stream>>>(edge_w2, eW2T, 256, 128, 256, t2);
        int t3 = 3 * 256 * 256;
        cvt_wT_kernel<<<(t3 + 255) / 256, 256, 0, stream>>>(node_w1, nW1T, 256, 256, 256, t3);
        cvt_wT_kernel<<<(t2 + 255) / 256, 256, 0, stream>>>(node_w2, nW2T, 256, 128, 256, t2);
    }

    prep_kernel<<<(N_EDGES + 255) / 256, 256, 0, stream>>>(positions, edge_shift, lattice,
                                                           edge_index, batch, d2);
    embed_kernel<<<(N_NODES * 128) / 256, 256, 0, stream>>>(embed_w, atomic_numbers, x, xb);

    // CSR counting sort by dst (packs src,dst,d2 per edge)
    {
        int nscan = (N_NODES + SCAN_BS - 1) / SCAN_BS;
        hist_kernel<<<(N_EDGES + 255) / 256, 256, 0, stream>>>(edge_index, deg);
        scan1_kernel<<<nscan, SCAN_BS, 0, stream>>>(deg, sc, bsum, N_NODES);
        scan2_kernel<<<1, 128, 0, stream>>>(bsum, nscan);
        scan3_kernel<<<(N_NODES + SCAN_BS) / SCAN_BS + 1, SCAN_BS, 0, stream>>>(
            sc, deg, bsum, rowptr, N_NODES, N_EDGES);
        fill_kernel<<<(N_EDGES + 255) / 256, 256, 0, stream>>>(edge_index, d2, rowptr, fillc,
                                                               epack);
    }

    const int nblk = (N_NODES + 63) / 64;
    for (int l = 0; l < N_LAYERS; l++) {
        y_precompute<<<nblk * 2, 256, 0, stream>>>(
            xb, WcT + (size_t)l * 512 * 128, edge_b1 + (size_t)l * 256, ydb, ysb);
        edge_mlp_csr<<<N_NODES / DQ, 256, 0, stream>>>(
            ydb, ysb, edge_w1 + ((size_t)l * 257 + 256) * 256, epack, rowptr,
            eW2T + (size_t)l * 128 * 256, edge_b2 + (size_t)l * 128, agg);
        node_mlp_mfma<<<nblk, 256, 0, stream>>>(
            x, xb, agg,
            nW1T + (size_t)l * 256 * 256, node_b1 + (size_t)l * 256,
            nW2T + (size_t)l * 128 * 256, node_b2 + (size_t)l * 128);
    }
    out_stage1<<<(N_NODES + 31) / 32, 256, 0, stream>>>(x, out_w1, out_b1, out_w2, out_b2, sval);
    out_stage2<<<OB2, 256, 0, stream>>>(sval, batch, partial);
    out_stage3<<<1, 64, 0, stream>>>(partial, (float*)d_out);
}